// Round 11
// baseline (287.592 us; speedup 1.0000x reference)
//
#include <hip/hip_runtime.h>
#include <hip/hip_fp16.h>
#include <math.h>
#include <stdint.h>

#define HH 512
#define WW 512
#define NIMG 24
#define CCH 3
#define TAU 0.25f
#define TVEPS 2e-4f
#define NUMEL 262144.0f

#define TSO 60      // owned tile (fused)
#define NT 9        // tiles per dim (fused): 9*60=540 covers 512

// LDS strides for tv_out's even-k recompute (round-2 verified)
#define LSF 69
#define LSH 70

// ws layout (256 MiB):
//   byte 0      : sc — 2 slots x 128 floats; slot s at sc+128*s:
//                 [0..23]=E_prev, [32..55]=E_init, int[64..87]=done, int[96..119]=last_k
//   byte 4096   : sums — float [2][4][NIMG][96]; slot=m&1; arrays 0=da,1=na,2=db,3=nb
//                 (step0 writes 64 partials into slot0/arr1; fused writes 81)
//   byte 131072 : imgh (__half, 24*512*512)
//   byte 12713984 : ptA (uint32 packed half2)
//   byte 37879808 : ptB

__device__ __forceinline__ float2 h2f(uint32_t v) {
    __half2 h; *reinterpret_cast<uint32_t*>(&h) = v;
    return __half22float2(h);
}
__device__ __forceinline__ uint32_t f2h2(float a, float b) {
    __half2 h = __floats2half2_rn(a, b);
    return *reinterpret_cast<uint32_t*>(&h);
}
__device__ __forceinline__ void h4_to_f(uint2 hv, float* f) {
    float2 a = h2f(hv.x), b = h2f(hv.y);
    f[0] = a.x; f[1] = a.y; f[2] = b.x; f[3] = b.y;
}

__device__ __forceinline__ int SUMIX(int slot, int arr, int im) {
    return ((slot * 4 + arr) * NIMG + im) * 96;
}

__device__ __forceinline__ void red4_store(float a, float b, float c, float d,
                                           float* pa, float* pb, float* pc, float* pdd,
                                           int tid) {
    for (int off = 32; off > 0; off >>= 1) {
        a += __shfl_down(a, off, 64);
        b += __shfl_down(b, off, 64);
        c += __shfl_down(c, off, 64);
        d += __shfl_down(d, off, 64);
    }
    __shared__ float sr[4][4];
    int wave = tid >> 6, lane = tid & 63;
    if (lane == 0) { sr[0][wave] = a; sr[1][wave] = b; sr[2][wave] = c; sr[3][wave] = d; }
    __syncthreads();
    if (tid == 0) {
        *pa = (sr[0][0] + sr[0][1]) + (sr[0][2] + sr[0][3]);
        *pb = (sr[1][0] + sr[1][1]) + (sr[1][2] + sr[1][3]);
        *pc = (sr[2][0] + sr[2][1]) + (sr[2][2] + sr[2][3]);
        *pdd = (sr[3][0] + sr[3][1]) + (sr[3][2] + sr[3][3]);
    }
}

// ---------- LDS helpers used ONLY by tv_out's even-k recompute (round-2 verified) ----------
struct Smem {
    uint32_t PT[68 * LSF];
    float    OA[68 * LSF];
    __half   IM[68 * LSH];
};

__device__ void stage_pt_im(Smem& S, const uint32_t* __restrict__ ptg,
                            const __half* __restrict__ hI,
                            int x0, int y0, int tid) {
    for (int idx = tid; idx < 68 * 34; idx += 256) {
        int r = idx / 34, mq = idx - r * 34;
        int c = 2 * mq;
        int y = y0 - 2 + r, x = x0 - 2 + c;
        uint2 pv = make_uint2(0u, 0u);
        uint32_t iv = 0u;
        if ((unsigned)y < (unsigned)HH && (unsigned)x < (unsigned)WW) {
            size_t off = (size_t)y * WW + x;
            pv = *(const uint2*)(ptg + off);
            iv = *(const uint32_t*)(hI + off);
        }
        S.PT[r * LSF + c] = pv.x;
        S.PT[r * LSF + c + 1] = pv.y;
        *(uint32_t*)&S.IM[r * LSH + c] = iv;
    }
}

__device__ void phase_outA_x(Smem& S, int tid) {
    for (int idx = tid; idx < 67 * 67; idx += 256) {
        int r = idx / 67, c = idx - r * 67;
        r += 1; c += 1;
        float2 cf = h2f(S.PT[r * LSF + c]);
        float up = h2f(S.PT[(r - 1) * LSF + c]).x;
        float lf = h2f(S.PT[r * LSF + c - 1]).y;
        float im = __half2float(S.IM[r * LSH + c]);
        S.OA[r * LSF + c] = im + (-(cf.x + cf.y) + up + lf);
    }
}

__device__ void phase_ptA_x(Smem& S, int x0, int y0, int tid, float tw) {
    for (int idx = tid; idx < 66 * 66; idx += 256) {
        int r = idx / 66, c = idx - r * 66;
        r += 1; c += 1;
        int y = y0 - 2 + r, x = x0 - 2 + c;
        if ((unsigned)y < (unsigned)HH && (unsigned)x < (unsigned)WW) {
            float o = S.OA[r * LSF + c];
            float g0 = (y < HH - 1) ? S.OA[(r + 1) * LSF + c] - o : 0.f;
            float g1 = (x < WW - 1) ? S.OA[r * LSF + c + 1] - o : 0.f;
            float ss2 = g0 * g0 + g1 * g1;
            float nrm = (ss2 > 0.f) ? sqrtf(ss2) : 0.f;
            float inv = __builtin_amdgcn_rcpf(1.f + tw * nrm);
            float2 cf = h2f(S.PT[r * LSF + c]);
            S.PT[r * LSF + c] = f2h2((cf.x - TAU * g0) * inv, (cf.y - TAU * g1) * inv);
        } else {
            S.PT[r * LSF + c] = 0u;
        }
    }
}

// =========================== iteration 0 (round-4 verbatim, partial idx 96-stride) ===========================
__global__ __launch_bounds__(256, 4) void tv_step0(
    const float* __restrict__ img, const float* __restrict__ weight,
    __half* __restrict__ imgh, uint32_t* __restrict__ ptout,
    float* __restrict__ pn0)
{
    const int im = blockIdx.z;
    const int bid = blockIdx.y * 8 + blockIdx.x;
    const float w = weight[im / CCH];
    const int x0 = blockIdx.x * 64, y0 = blockIdx.y * 64;
    const float* imgI = img + (size_t)im * HH * WW;
    __half* hI = imgh + (size_t)im * HH * WW;
    uint32_t* pI = ptout + (size_t)im * HH * WW;
    __shared__ float s[65][68];
    const int tid = threadIdx.x;
    const int tx = tid & 15, ry = tid >> 4;
    const int gx = x0 + 4 * tx;

    float o[4][4];
    #pragma unroll
    for (int i = 0; i < 4; ++i) {
        int ey = ry + 16 * i, gy = y0 + ey;
        float4 v = *(const float4*)(imgI + (size_t)gy * WW + gx);
        o[i][0] = v.x; o[i][1] = v.y; o[i][2] = v.z; o[i][3] = v.w;
        *(float4*)&s[ey][4 * tx] = v;
    }
    if (tx == 15 && x0 + 64 < WW) {
        #pragma unroll
        for (int i = 0; i < 4; ++i) {
            int ey = ry + 16 * i, gy = y0 + ey;
            s[ey][64] = imgI[(size_t)gy * WW + x0 + 64];
        }
    }
    if (ry == 0 && y0 + 64 < HH) {
        *(float4*)&s[64][4 * tx] = *(const float4*)(imgI + (size_t)(y0 + 64) * WW + gx);
    }
    __syncthreads();

    float accn = 0.f;
    const float tw = TAU / w;
    #pragma unroll
    for (int i = 0; i < 4; ++i) {
        int ey = ry + 16 * i, gy = y0 + ey;
        float4 dn = *(float4*)&s[ey + 1][4 * tx];
        float rt_sh = __shfl_down(o[i][0], 1, 64);
        float rt = (tx == 15) ? s[ey][64] : rt_sh;
        float dnv[4] = {dn.x, dn.y, dn.z, dn.w};
        uint32_t pv[4];
        #pragma unroll
        for (int j = 0; j < 4; ++j) {
            float ov = o[i][j];
            float g0 = (gy < HH - 1) ? dnv[j] - ov : 0.f;
            float rn = (j < 3) ? o[i][j + 1] : rt;
            float g1 = (gx + j < WW - 1) ? rn - ov : 0.f;
            float ss2 = g0 * g0 + g1 * g1;
            float nrm = (ss2 > 0.f) ? sqrtf(ss2) : 0.f;
            accn += nrm;
            float inv = __builtin_amdgcn_rcpf(1.f + tw * nrm);
            pv[j] = f2h2(-TAU * g0 * inv, -TAU * g1 * inv);
        }
        size_t off = (size_t)gy * WW + gx;
        *(uint4*)(pI + off) = make_uint4(pv[0], pv[1], pv[2], pv[3]);
        *(uint2*)(hI + off) = make_uint2(f2h2(o[i][0], o[i][1]), f2h2(o[i][2], o[i][3]));
    }
    for (int off = 32; off > 0; off >>= 1) accn += __shfl_down(accn, off, 64);
    __shared__ float sr[4];
    if ((tid & 63) == 0) sr[tid >> 6] = accn;
    __syncthreads();
    if (tid == 0) pn0[im * 96 + bid] = (sr[0] + sr[1]) + (sr[2] + sr[3]);
}

// ============ fused pair (iterations 2m-1, 2m): uniform shrinking-window ============
// 64x64 loaded window (halo 2), 60x60 owned output, NO edge-special code.
// launch_bounds(256,4): measured VGPR=84 fits the 128 cap -> 16 waves/CU (was 12).
__global__ __launch_bounds__(256, 4) void tv_fused(
    int m,
    const __half* __restrict__ imgh, const float* __restrict__ weight,
    const uint32_t* __restrict__ pt_in, uint32_t* __restrict__ pt_out,
    float* __restrict__ sc, float* __restrict__ sums)
{
    const int im = blockIdx.z;
    const int bx = blockIdx.x, by = blockIdx.y;
    const int bid = by * NT + bx;     // 0..80
    const int tid = threadIdx.x;
    const float w = weight[im / CCH];

    // --- replay head: two-wave deterministic reduce of previous kernel's partials ---
    __shared__ int sh_done;
    __shared__ float hsum[2][4];
    {
        const int sIn = (m - 1) & 1;
        float da = 0.f, na = 0.f, db = 0.f, nb = 0.f;
        if (m == 1) {
            if (tid < 64) na = sums[SUMIX(0, 1, im) + tid];
        } else if (tid < 81) {
            da = sums[SUMIX(sIn, 0, im) + tid];
            na = sums[SUMIX(sIn, 1, im) + tid];
            db = sums[SUMIX(sIn, 2, im) + tid];
            nb = sums[SUMIX(sIn, 3, im) + tid];
        }
        if (tid < 128) {
            for (int off = 32; off > 0; off >>= 1) {
                da += __shfl_down(da, off, 64);
                na += __shfl_down(na, off, 64);
                db += __shfl_down(db, off, 64);
                nb += __shfl_down(nb, off, 64);
            }
            if ((tid & 63) == 0) {
                hsum[tid >> 6][0] = da; hsum[tid >> 6][1] = na;
                hsum[tid >> 6][2] = db; hsum[tid >> 6][3] = nb;
            }
        }
        __syncthreads();
        if (tid == 0) {
            float tda = hsum[0][0] + hsum[1][0];
            float tna = hsum[0][1] + hsum[1][1];
            float tdb = hsum[0][2] + hsum[1][2];
            float tnb = hsum[0][3] + hsum[1][3];
            float Eprev, Einit; int done, lastk;
            if (m == 1) {
                float E0 = w * tna / NUMEL;
                Eprev = E0; Einit = E0; done = 0; lastk = 0;
            } else {
                const float* sI = sc + ((m - 1) & 1) * 128;
                Eprev = sI[im]; Einit = sI[32 + im];
                done = ((const int*)sI)[64 + im];
                lastk = ((const int*)sI)[96 + im];
                if (!done) {
                    float Et = (tda + w * tna) / NUMEL;           // iter 2m-3
                    if (fabsf(Eprev - Et) < TVEPS * Einit) { done = 1; lastk = 2 * m - 3; }
                    else {
                        Eprev = Et;
                        Et = (tdb + w * tnb) / NUMEL;             // iter 2m-2
                        if (fabsf(Eprev - Et) < TVEPS * Einit) { done = 1; lastk = 2 * m - 2; }
                        else Eprev = Et;
                    }
                }
            }
            if (bid == 0) {
                float* sO = sc + (m & 1) * 128;
                sO[im] = Eprev; sO[32 + im] = Einit;
                ((int*)sO)[64 + im] = done;
                ((int*)sO)[96 + im] = lastk;
            }
            sh_done = done;
        }
    }
    __syncthreads();
    if (sh_done) return;

    const float tw = TAU / w;
    const uint32_t* pinI = pt_in + (size_t)im * HH * WW;
    uint32_t* poutI = pt_out + (size_t)im * HH * WW;
    const __half* hI = imgh + (size_t)im * HH * WW;

    const int tx = tid & 15, ty = tid >> 4;
    const int wx0 = TSO * bx - 2, wy0 = TSO * by - 2;
    const int cx0 = wx0 + 4 * tx;         // col of j=0
    const int ry0 = wy0 + 4 * ty;         // row of i=0

    __shared__ uint4  XP[16][16];
    __shared__ float4 XO[16][16];

    // ---- loads: 4 rows x 4 cols of pt + img (window; OOB -> 0) ----
    uint32_t c[4][4];
    uint32_t ihp[4][2];   // packed img halves
    const bool interior = (wx0 >= 0) && (wx0 + 64 <= WW) && (wy0 >= 0) && (wy0 + 64 <= HH);
    if (interior) {
        #pragma unroll
        for (int i = 0; i < 4; ++i) {
            size_t off = (size_t)(ry0 + i) * WW + cx0;
            uint2 a = *(const uint2*)(pinI + off);
            uint2 b = *(const uint2*)(pinI + off + 2);
            c[i][0] = a.x; c[i][1] = a.y; c[i][2] = b.x; c[i][3] = b.y;
            ihp[i][0] = *(const uint32_t*)(hI + off);
            ihp[i][1] = *(const uint32_t*)(hI + off + 2);
        }
    } else {
        #pragma unroll
        for (int i = 0; i < 4; ++i) {
            int gy = ry0 + i;
            unsigned short us[4];
            #pragma unroll
            for (int j = 0; j < 4; ++j) {
                int gxj = cx0 + j;
                bool in = ((unsigned)gy < (unsigned)HH) && ((unsigned)gxj < (unsigned)WW);
                c[i][j] = in ? pinI[(size_t)gy * WW + gxj] : 0u;
                us[j] = in ? *(const unsigned short*)(hI + (size_t)gy * WW + gxj)
                           : (unsigned short)0;
            }
            ihp[i][0] = (uint32_t)us[0] | ((uint32_t)us[1] << 16);
            ihp[i][1] = (uint32_t)us[2] | ((uint32_t)us[3] << 16);
        }
    }
    XP[ty][tx] = make_uint4(c[3][0], c[3][1], c[3][2], c[3][3]);
    __syncthreads();   // s1

    // ================= OUT_A (valid r,c in [1,63]) =================
    float o[4][4];
    float accda = 0.f;
    {
        uint4 up4 = (ty > 0) ? XP[ty - 1][tx] : make_uint4(0u, 0u, 0u, 0u);
        uint32_t ua[4] = {up4.x, up4.y, up4.z, up4.w};
        #pragma unroll
        for (int i = 0; i < 4; ++i) {
            uint32_t lw = __shfl_up(c[i][3], 1, 64);
            int gy = ry0 + i;
            bool r_ok = (unsigned)(4 * ty + i - 2) < 60u && gy < HH;
            #pragma unroll
            for (int j = 0; j < 4; ++j) {
                float2 cf = h2f(c[i][j]);
                float up = (i > 0) ? h2f(c[i - 1][j]).x : h2f(ua[j]).x;
                float le = (j > 0) ? h2f(c[i][j - 1]).y : h2f(lw).y;
                float dv = -(cf.x + cf.y) + up + le;
                float2 i2 = h2f(ihp[i][j >> 1]);
                float imv = (j & 1) ? i2.y : i2.x;
                o[i][j] = imv + dv;
                bool own = r_ok && ((unsigned)(4 * tx + j - 2) < 60u) && (cx0 + j < WW);
                accda += own ? dv * dv : 0.f;
            }
        }
    }

    // ================= PT_A (valid r,c in [1,62]; zeroed outside image) =================
    uint32_t pa[4][4];
    float accna = 0.f;
    XO[ty][tx] = make_float4(o[0][0], o[0][1], o[0][2], o[0][3]);
    __syncthreads();   // s2
    {
        float4 b4 = (ty < 15) ? XO[ty + 1][tx] : make_float4(0.f, 0.f, 0.f, 0.f);
        float bel[4] = {b4.x, b4.y, b4.z, b4.w};
        #pragma unroll
        for (int i = 0; i < 4; ++i) {
            float rsh = __shfl_down(o[i][0], 1, 64);
            int gy = ry0 + i;
            bool r_ok = (unsigned)(4 * ty + i - 2) < 60u && gy < HH;
            #pragma unroll
            for (int j = 0; j < 4; ++j) {
                int gxj = cx0 + j;
                float ov = o[i][j];
                float below = (i < 3) ? o[i + 1][j] : bel[j];
                float right = (j < 3) ? o[i][j + 1] : rsh;
                float g0 = (gy < HH - 1) ? below - ov : 0.f;
                float g1 = (gxj < WW - 1) ? right - ov : 0.f;
                float ss2 = g0 * g0 + g1 * g1;
                float nrm = (ss2 > 0.f) ? sqrtf(ss2) : 0.f;
                float inv = __builtin_amdgcn_rcpf(1.f + tw * nrm);
                float2 cf = h2f(c[i][j]);
                uint32_t pvv = f2h2((cf.x - TAU * g0) * inv, (cf.y - TAU * g1) * inv);
                bool vp = ((unsigned)gy < (unsigned)HH) && ((unsigned)gxj < (unsigned)WW);
                pa[i][j] = vp ? pvv : 0u;
                bool own = r_ok && ((unsigned)(4 * tx + j - 2) < 60u) && (gxj < WW);
                accna += own ? nrm : 0.f;
            }
        }
    }

    // ================= OUT_B (valid r,c in [2,62]) =================
    float ob[4][4];
    float accdb = 0.f;
    XP[ty][tx] = make_uint4(pa[3][0], pa[3][1], pa[3][2], pa[3][3]);
    __syncthreads();   // s3
    {
        uint4 up4 = (ty > 0) ? XP[ty - 1][tx] : make_uint4(0u, 0u, 0u, 0u);
        uint32_t ua[4] = {up4.x, up4.y, up4.z, up4.w};
        #pragma unroll
        for (int i = 0; i < 4; ++i) {
            uint32_t lw = __shfl_up(pa[i][3], 1, 64);
            int gy = ry0 + i;
            bool r_ok = (unsigned)(4 * ty + i - 2) < 60u && gy < HH;
            #pragma unroll
            for (int j = 0; j < 4; ++j) {
                float2 cf = h2f(pa[i][j]);
                float up = (i > 0) ? h2f(pa[i - 1][j]).x : h2f(ua[j]).x;
                float le = (j > 0) ? h2f(pa[i][j - 1]).y : h2f(lw).y;
                float dv = -(cf.x + cf.y) + up + le;
                float2 i2 = h2f(ihp[i][j >> 1]);
                float imv = (j & 1) ? i2.y : i2.x;
                ob[i][j] = imv + dv;
                bool own = r_ok && ((unsigned)(4 * tx + j - 2) < 60u) && (cx0 + j < WW);
                accdb += own ? dv * dv : 0.f;
            }
        }
    }

    // ================= PT_B (owned r,c in [2,61]) + store =================
    float accnb = 0.f;
    XO[ty][tx] = make_float4(ob[0][0], ob[0][1], ob[0][2], ob[0][3]);
    __syncthreads();   // s4
    {
        float4 b4 = (ty < 15) ? XO[ty + 1][tx] : make_float4(0.f, 0.f, 0.f, 0.f);
        float bel[4] = {b4.x, b4.y, b4.z, b4.w};
        #pragma unroll
        for (int i = 0; i < 4; ++i) {
            float rsh = __shfl_down(ob[i][0], 1, 64);
            int gy = ry0 + i;
            bool r_ok = ((unsigned)(4 * ty + i - 2) < 60u) && (gy < HH);
            uint32_t pv[4];
            #pragma unroll
            for (int j = 0; j < 4; ++j) {
                int gxj = cx0 + j;
                float ov = ob[i][j];
                float below = (i < 3) ? ob[i + 1][j] : bel[j];
                float right = (j < 3) ? ob[i][j + 1] : rsh;
                float g0 = (gy < HH - 1) ? below - ov : 0.f;
                float g1 = (gxj < WW - 1) ? right - ov : 0.f;
                float ss2 = g0 * g0 + g1 * g1;
                float nrm = (ss2 > 0.f) ? sqrtf(ss2) : 0.f;
                float inv = __builtin_amdgcn_rcpf(1.f + tw * nrm);
                float2 cf = h2f(pa[i][j]);
                uint32_t pvv = f2h2((cf.x - TAU * g0) * inv, (cf.y - TAU * g1) * inv);
                bool vp = ((unsigned)gy < (unsigned)HH) && ((unsigned)gxj < (unsigned)WW);
                pv[j] = vp ? pvv : 0u;
                bool own = r_ok && ((unsigned)(4 * tx + j - 2) < 60u) && (gxj < WW);
                accnb += own ? nrm : 0.f;
            }
            if (r_ok) {
                size_t off = (size_t)gy * WW + cx0;
                if (tx > 0 && cx0 < WW)
                    *(uint2*)(poutI + off) = make_uint2(pv[0], pv[1]);
                if (tx < 15 && cx0 + 2 < WW)
                    *(uint2*)(poutI + off + 2) = make_uint2(pv[2], pv[3]);
            }
        }
    }

    const int sOut = m & 1;
    red4_store(accda, accna, accdb, accnb,
               &sums[SUMIX(sOut, 0, im) + bid], &sums[SUMIX(sOut, 1, im) + bid],
               &sums[SUMIX(sOut, 2, im) + bid], &sums[SUMIX(sOut, 3, im) + bid], tid);
}

// =========================== epilogue (R5 logic, 81-partial head) ===========================
__global__ __launch_bounds__(256, 3) void tv_out(
    const float* __restrict__ img, float* __restrict__ out,
    const uint32_t* __restrict__ ptA, const uint32_t* __restrict__ ptB,
    const __half* __restrict__ imgh, const float* __restrict__ weight,
    const float* __restrict__ sc, const float* __restrict__ sums)
{
    const int im = blockIdx.z;
    const int tid = threadIdx.x;
    const float w = weight[im / CCH];

    __shared__ int2 shk;
    __shared__ float hsum[2][4];
    {
        const float* sI = sc;   // slot 0 = S_6 (written by m=4)
        int done = ((const int*)sI)[64 + im];
        int lastk = ((const int*)sI)[96 + im];
        float da = 0.f, na = 0.f, db = 0.f, nb = 0.f;
        if (!done && tid < 81) {
            da = sums[SUMIX(0, 0, im) + tid];
            na = sums[SUMIX(0, 1, im) + tid];
            db = sums[SUMIX(0, 2, im) + tid];
            nb = sums[SUMIX(0, 3, im) + tid];
        }
        if (tid < 128) {
            for (int off = 32; off > 0; off >>= 1) {
                da += __shfl_down(da, off, 64);
                na += __shfl_down(na, off, 64);
                db += __shfl_down(db, off, 64);
                nb += __shfl_down(nb, off, 64);
            }
            if ((tid & 63) == 0) {
                hsum[tid >> 6][0] = da; hsum[tid >> 6][1] = na;
                hsum[tid >> 6][2] = db; hsum[tid >> 6][3] = nb;
            }
        }
        __syncthreads();
        if (tid == 0) {
            if (!done) {
                float tda = hsum[0][0] + hsum[1][0];
                float tna = hsum[0][1] + hsum[1][1];
                float tdb = hsum[0][2] + hsum[1][2];
                float tnb = hsum[0][3] + hsum[1][3];
                float Eprev = sI[im], Einit = sI[32 + im];
                float Et = (tda + w * tna) / NUMEL;                // iter 7
                if (fabsf(Eprev - Et) < TVEPS * Einit) { done = 1; lastk = 7; }
                else {
                    Eprev = Et;
                    Et = (tdb + w * tnb) / NUMEL;                  // iter 8
                    if (fabsf(Eprev - Et) < TVEPS * Einit) { done = 1; lastk = 8; }
                }
            }
            shk.x = done; shk.y = lastk;
        }
    }
    __syncthreads();
    const int k = shk.x ? shk.y : 9;

    const float* imgI = img + (size_t)im * HH * WW;
    float* outI = out + (size_t)im * HH * WW;
    const int x0 = blockIdx.x * 64, y0 = blockIdx.y * 64;
    const int tx = tid & 15, ry = tid >> 4;
    const int gx = x0 + 4 * tx;

    if (k & 1) {
        // k in {1,3,5,7,9}: pt_{k-1} materialized. pt_0:A pt_2:B pt_4:A pt_6:B pt_8:A
        const uint32_t* p = ((((k - 1) >> 1) & 1) ? ptB : ptA) + (size_t)im * HH * WW;
        #pragma unroll
        for (int i = 0; i < 4; ++i) {
            int gy = y0 + ry + 16 * i;
            size_t off = (size_t)gy * WW + gx;
            uint4 cv = *(const uint4*)(p + off);
            uint4 uv = make_uint4(0u, 0u, 0u, 0u);
            if (gy > 0) uv = *(const uint4*)(p + off - WW);
            uint32_t lf = (gx > 0) ? p[off - 1] : 0u;
            float4 iv = *(const float4*)(imgI + off);
            uint32_t cc[4] = {cv.x, cv.y, cv.z, cv.w};
            uint32_t uu[4] = {uv.x, uv.y, uv.z, uv.w};
            uint32_t lt[4] = {lf, cv.x, cv.y, cv.z};
            float ivv[4] = {iv.x, iv.y, iv.z, iv.w};
            float r[4];
            #pragma unroll
            for (int j = 0; j < 4; ++j) {
                float2 cf = h2f(cc[j]);
                r[j] = ivv[j] + (-(cf.x + cf.y) + h2f(uu[j]).x + h2f(lt[j]).y);
            }
            *(float4*)(outI + off) = make_float4(r[0], r[1], r[2], r[3]);
        }
    } else {
        // k in {2,4,6,8}: recompute pt_{k-1} from preserved pt_{k-2}.
        const uint32_t* p = ((((k - 2) >> 1) & 1) ? ptB : ptA) + (size_t)im * HH * WW;
        const __half* hI = imgh + (size_t)im * HH * WW;
        const float tw = TAU / w;
        __shared__ Smem S;
        stage_pt_im(S, p, hI, x0, y0, tid);
        __syncthreads();
        phase_outA_x(S, tid);
        __syncthreads();
        phase_ptA_x(S, x0, y0, tid, tw);
        __syncthreads();
        #pragma unroll
        for (int i = 0; i < 4; ++i) {
            int gy = y0 + ry + 16 * i;
            int r = 2 + ry + 16 * i;
            size_t off = (size_t)gy * WW + gx;
            float4 iv = *(const float4*)(imgI + off);
            float ivv[4] = {iv.x, iv.y, iv.z, iv.w};
            float rr[4];
            #pragma unroll
            for (int j = 0; j < 4; ++j) {
                int cix = 2 + 4 * tx + j;
                float2 cf = h2f(S.PT[r * LSF + cix]);
                float up = h2f(S.PT[(r - 1) * LSF + cix]).x;
                float lf = h2f(S.PT[r * LSF + cix - 1]).y;
                rr[j] = ivv[j] + (-(cf.x + cf.y) + up + lf);
            }
            *(float4*)(outI + off) = make_float4(rr[0], rr[1], rr[2], rr[3]);
        }
    }
}

extern "C" void kernel_launch(void* const* d_in, const int* in_sizes, int n_in,
                              void* d_out, int out_size, void* d_ws, size_t ws_size,
                              hipStream_t stream)
{
    const float* img = (const float*)d_in[0];
    const float* weight = (const float*)d_in[1];
    float* out = (float*)d_out;
    float* sc = (float*)d_ws;
    float* sums = (float*)((char*)d_ws + 4096);
    __half* imgh = (__half*)((char*)d_ws + 131072);
    uint32_t* ptA = (uint32_t*)((char*)d_ws + 12713984);
    uint32_t* ptB = (uint32_t*)((char*)d_ws + 37879808);

    dim3 block(256);

    // iteration 0 -> pt_0 in A; accn into sums slot0/arr1 (64 partials)
    float* pn0 = sums + 1 * NIMG * 96;   // SUMIX(0,1,·) base
    tv_step0<<<dim3(8, 8, NIMG), block, 0, stream>>>(img, weight, imgh, ptA, pn0);

    // fused pairs m=1..4 cover iterations 1..8; m odd A->B, m even B->A
    for (int m = 1; m <= 4; ++m) {
        uint32_t* pin  = (m & 1) ? ptA : ptB;
        uint32_t* pout = (m & 1) ? ptB : ptA;
        tv_fused<<<dim3(NT, NT, NIMG), block, 0, stream>>>(m, imgh, weight, pin, pout, sc, sums);
    }

    // iteration 9's pt is dead; epilogue replays iters 7,8 and emits out.
    tv_out<<<dim3(8, 8, NIMG), block, 0, stream>>>(img, out, ptA, ptB, imgh, weight, sc, sums);
}

// Round 12
// 225.268 us; speedup vs baseline: 1.2767x; 1.2767x over previous
//
#include <hip/hip_runtime.h>
#include <hip/hip_fp16.h>
#include <math.h>
#include <stdint.h>

#define HH 512
#define WW 512
#define NIMG 24
#define CCH 3
#define TAU 0.25f
#define TVEPS 2e-4f
#define NUMEL 262144.0f

#define NTB 10      // block tiles per dim: 10*56=560 covers 512 (block = 2x2 waves of 28)

// LDS strides for tv_out's even-k recompute (round-2 verified)
#define LSF 69
#define LSH 70

// ws layout (256 MiB):
//   byte 0      : sc — 2 slots x 128 floats; slot s at sc+128*s:
//                 [0..23]=E_prev, [32..55]=E_init, int[64..87]=done, int[96..119]=last_k
//   byte 4096   : sums — float [2][4][NIMG][128]; slot=m&1; arrays 0=da,1=na,2=db,3=nb
//                 (step0 writes 64 partials into slot0/arr1; fused writes 100)
//   byte 131072 : imgh (__half, 24*512*512)
//   byte 12713984 : ptA (uint32 packed half2)
//   byte 37879808 : ptB

__device__ __forceinline__ float2 h2f(uint32_t v) {
    __half2 h; *reinterpret_cast<uint32_t*>(&h) = v;
    return __half22float2(h);
}
__device__ __forceinline__ uint32_t f2h2(float a, float b) {
    __half2 h = __floats2half2_rn(a, b);
    return *reinterpret_cast<uint32_t*>(&h);
}

__device__ __forceinline__ int SUMIX(int slot, int arr, int im) {
    return ((slot * 4 + arr) * NIMG + im) * 128;
}

__device__ __forceinline__ void red4_store(float a, float b, float c, float d,
                                           float* pa, float* pb, float* pc, float* pdd,
                                           int tid) {
    for (int off = 32; off > 0; off >>= 1) {
        a += __shfl_down(a, off, 64);
        b += __shfl_down(b, off, 64);
        c += __shfl_down(c, off, 64);
        d += __shfl_down(d, off, 64);
    }
    __shared__ float sr[4][4];
    int wave = tid >> 6, lane = tid & 63;
    if (lane == 0) { sr[0][wave] = a; sr[1][wave] = b; sr[2][wave] = c; sr[3][wave] = d; }
    __syncthreads();
    if (tid == 0) {
        *pa = (sr[0][0] + sr[0][1]) + (sr[0][2] + sr[0][3]);
        *pb = (sr[1][0] + sr[1][1]) + (sr[1][2] + sr[1][3]);
        *pc = (sr[2][0] + sr[2][1]) + (sr[2][2] + sr[2][3]);
        *pdd = (sr[3][0] + sr[3][1]) + (sr[3][2] + sr[3][3]);
    }
}

// ---------- LDS helpers used ONLY by tv_out's even-k recompute (round-2 verified) ----------
struct Smem {
    uint32_t PT[68 * LSF];
    float    OA[68 * LSF];
    __half   IM[68 * LSH];
};

__device__ void stage_pt_im(Smem& S, const uint32_t* __restrict__ ptg,
                            const __half* __restrict__ hI,
                            int x0, int y0, int tid) {
    for (int idx = tid; idx < 68 * 34; idx += 256) {
        int r = idx / 34, mq = idx - r * 34;
        int c = 2 * mq;
        int y = y0 - 2 + r, x = x0 - 2 + c;
        uint2 pv = make_uint2(0u, 0u);
        uint32_t iv = 0u;
        if ((unsigned)y < (unsigned)HH && (unsigned)x < (unsigned)WW) {
            size_t off = (size_t)y * WW + x;
            pv = *(const uint2*)(ptg + off);
            iv = *(const uint32_t*)(hI + off);
        }
        S.PT[r * LSF + c] = pv.x;
        S.PT[r * LSF + c + 1] = pv.y;
        *(uint32_t*)&S.IM[r * LSH + c] = iv;
    }
}

__device__ void phase_outA_x(Smem& S, int tid) {
    for (int idx = tid; idx < 67 * 67; idx += 256) {
        int r = idx / 67, c = idx - r * 67;
        r += 1; c += 1;
        float2 cf = h2f(S.PT[r * LSF + c]);
        float up = h2f(S.PT[(r - 1) * LSF + c]).x;
        float lf = h2f(S.PT[r * LSF + c - 1]).y;
        float im = __half2float(S.IM[r * LSH + c]);
        S.OA[r * LSF + c] = im + (-(cf.x + cf.y) + up + lf);
    }
}

__device__ void phase_ptA_x(Smem& S, int x0, int y0, int tid, float tw) {
    for (int idx = tid; idx < 66 * 66; idx += 256) {
        int r = idx / 66, c = idx - r * 66;
        r += 1; c += 1;
        int y = y0 - 2 + r, x = x0 - 2 + c;
        if ((unsigned)y < (unsigned)HH && (unsigned)x < (unsigned)WW) {
            float o = S.OA[r * LSF + c];
            float g0 = (y < HH - 1) ? S.OA[(r + 1) * LSF + c] - o : 0.f;
            float g1 = (x < WW - 1) ? S.OA[r * LSF + c + 1] - o : 0.f;
            float ss2 = g0 * g0 + g1 * g1;
            float nrm = (ss2 > 0.f) ? sqrtf(ss2) : 0.f;
            float inv = __builtin_amdgcn_rcpf(1.f + tw * nrm);
            float2 cf = h2f(S.PT[r * LSF + c]);
            S.PT[r * LSF + c] = f2h2((cf.x - TAU * g0) * inv, (cf.y - TAU * g1) * inv);
        } else {
            S.PT[r * LSF + c] = 0u;
        }
    }
}

// =========================== iteration 0 (round-4 verbatim, 128-stride partials) ===========================
__global__ __launch_bounds__(256, 4) void tv_step0(
    const float* __restrict__ img, const float* __restrict__ weight,
    __half* __restrict__ imgh, uint32_t* __restrict__ ptout,
    float* __restrict__ pn0)
{
    const int im = blockIdx.z;
    const int bid = blockIdx.y * 8 + blockIdx.x;
    const float w = weight[im / CCH];
    const int x0 = blockIdx.x * 64, y0 = blockIdx.y * 64;
    const float* imgI = img + (size_t)im * HH * WW;
    __half* hI = imgh + (size_t)im * HH * WW;
    uint32_t* pI = ptout + (size_t)im * HH * WW;
    __shared__ float s[65][68];
    const int tid = threadIdx.x;
    const int tx = tid & 15, ry = tid >> 4;
    const int gx = x0 + 4 * tx;

    float o[4][4];
    #pragma unroll
    for (int i = 0; i < 4; ++i) {
        int ey = ry + 16 * i, gy = y0 + ey;
        float4 v = *(const float4*)(imgI + (size_t)gy * WW + gx);
        o[i][0] = v.x; o[i][1] = v.y; o[i][2] = v.z; o[i][3] = v.w;
        *(float4*)&s[ey][4 * tx] = v;
    }
    if (tx == 15 && x0 + 64 < WW) {
        #pragma unroll
        for (int i = 0; i < 4; ++i) {
            int ey = ry + 16 * i, gy = y0 + ey;
            s[ey][64] = imgI[(size_t)gy * WW + x0 + 64];
        }
    }
    if (ry == 0 && y0 + 64 < HH) {
        *(float4*)&s[64][4 * tx] = *(const float4*)(imgI + (size_t)(y0 + 64) * WW + gx);
    }
    __syncthreads();

    float accn = 0.f;
    const float tw = TAU / w;
    #pragma unroll
    for (int i = 0; i < 4; ++i) {
        int ey = ry + 16 * i, gy = y0 + ey;
        float4 dn = *(float4*)&s[ey + 1][4 * tx];
        float rt_sh = __shfl_down(o[i][0], 1, 64);
        float rt = (tx == 15) ? s[ey][64] : rt_sh;
        float dnv[4] = {dn.x, dn.y, dn.z, dn.w};
        uint32_t pv[4];
        #pragma unroll
        for (int j = 0; j < 4; ++j) {
            float ov = o[i][j];
            float g0 = (gy < HH - 1) ? dnv[j] - ov : 0.f;
            float rn = (j < 3) ? o[i][j + 1] : rt;
            float g1 = (gx + j < WW - 1) ? rn - ov : 0.f;
            float ss2 = g0 * g0 + g1 * g1;
            float nrm = (ss2 > 0.f) ? sqrtf(ss2) : 0.f;
            accn += nrm;
            float inv = __builtin_amdgcn_rcpf(1.f + tw * nrm);
            pv[j] = f2h2(-TAU * g0 * inv, -TAU * g1 * inv);
        }
        size_t off = (size_t)gy * WW + gx;
        *(uint4*)(pI + off) = make_uint4(pv[0], pv[1], pv[2], pv[3]);
        *(uint2*)(hI + off) = make_uint2(f2h2(o[i][0], o[i][1]), f2h2(o[i][2], o[i][3]));
    }
    for (int off = 32; off > 0; off >>= 1) accn += __shfl_down(accn, off, 64);
    __shared__ float sr[4];
    if ((tid & 63) == 0) sr[tid >> 6] = accn;
    __syncthreads();
    if (tid == 0) pn0[im * 128 + bid] = (sr[0] + sr[1]) + (sr[2] + sr[3]);
}

// ============ fused pair (iterations 2m-1, 2m): wave-local 32x32 window ============
// Each WAVE owns 28x28 (window 32x32, halo 2). All neighbor exchange via shuffles:
// up/down = shfl +-8, left/right = shfl +-1. ZERO inter-phase barriers.
__global__ __launch_bounds__(256, 3) void tv_fused(
    int m,
    const __half* __restrict__ imgh, const float* __restrict__ weight,
    const uint32_t* __restrict__ pt_in, uint32_t* __restrict__ pt_out,
    float* __restrict__ sc, float* __restrict__ sums)
{
    const int im = blockIdx.z;
    const int bx = blockIdx.x, by = blockIdx.y;
    const int bid = by * NTB + bx;     // 0..99
    const int tid = threadIdx.x;
    const int lane = tid & 63, wid = tid >> 6;
    const float w = weight[im / CCH];

    // ---- per-wave replay head (redundant in each wave; no cross-wave sync) ----
    int done, lastk;
    float Eprev, Einit;
    {
        const int sIn = (m - 1) & 1;
        float da = 0.f, na = 0.f, db = 0.f, nb = 0.f;
        if (m == 1) {
            na = sums[SUMIX(0, 1, im) + lane];                 // 64 partials
        } else {
            da = sums[SUMIX(sIn, 0, im) + lane];               // 100 partials
            na = sums[SUMIX(sIn, 1, im) + lane];
            db = sums[SUMIX(sIn, 2, im) + lane];
            nb = sums[SUMIX(sIn, 3, im) + lane];
            if (lane < 36) {
                da += sums[SUMIX(sIn, 0, im) + 64 + lane];
                na += sums[SUMIX(sIn, 1, im) + 64 + lane];
                db += sums[SUMIX(sIn, 2, im) + 64 + lane];
                nb += sums[SUMIX(sIn, 3, im) + 64 + lane];
            }
        }
        for (int off = 32; off > 0; off >>= 1) {
            da += __shfl_down(da, off, 64);
            na += __shfl_down(na, off, 64);
            db += __shfl_down(db, off, 64);
            nb += __shfl_down(nb, off, 64);
        }
        float tda = __shfl(da, 0, 64), tna = __shfl(na, 0, 64);
        float tdb = __shfl(db, 0, 64), tnb = __shfl(nb, 0, 64);
        if (m == 1) {
            float E0 = w * tna / NUMEL;
            Eprev = E0; Einit = E0; done = 0; lastk = 0;
        } else {
            const float* sI = sc + ((m - 1) & 1) * 128;
            Eprev = sI[im]; Einit = sI[32 + im];
            done = ((const int*)sI)[64 + im];
            lastk = ((const int*)sI)[96 + im];
            if (!done) {
                float Et = (tda + w * tna) / NUMEL;            // iter 2m-3
                if (fabsf(Eprev - Et) < TVEPS * Einit) { done = 1; lastk = 2 * m - 3; }
                else {
                    Eprev = Et;
                    Et = (tdb + w * tnb) / NUMEL;              // iter 2m-2
                    if (fabsf(Eprev - Et) < TVEPS * Einit) { done = 1; lastk = 2 * m - 2; }
                    else Eprev = Et;
                }
            }
        }
        if (bid == 0 && tid == 0) {
            float* sO = sc + (m & 1) * 128;
            sO[im] = Eprev; sO[32 + im] = Einit;
            ((int*)sO)[64 + im] = done;
            ((int*)sO)[96 + im] = lastk;
        }
    }
    if (done) return;   // identical decision in every wave/block -> consistent

    const float tw = TAU / w;
    const uint32_t* pinI = pt_in + (size_t)im * HH * WW;
    uint32_t* poutI = pt_out + (size_t)im * HH * WW;
    const __half* hI = imgh + (size_t)im * HH * WW;

    // wave tile geometry: block owns 56x56 (2x2 waves of 28); window 32x32 per wave
    const int wxq = wid & 1, wyq = wid >> 1;
    const int lx = lane & 7, ly = lane >> 3;
    const int ox0 = 56 * bx + 28 * wxq;          // owned origin (col)
    const int oy0 = 56 * by + 28 * wyq;          // owned origin (row)
    const int cx0 = ox0 - 2 + 4 * lx;            // window col of j=0
    const int ry0 = oy0 - 2 + 4 * ly;            // window row of i=0

    // ---- loads: 4 rows x 4 cols of pt + img (window; OOB -> 0) ----
    uint32_t c[4][4];
    uint32_t ihp[4][2];
    const bool interior = (ox0 >= 2) && (ox0 + 30 <= WW) && (oy0 >= 2) && (oy0 + 30 <= HH);
    if (interior) {
        #pragma unroll
        for (int i = 0; i < 4; ++i) {
            size_t off = (size_t)(ry0 + i) * WW + cx0;
            uint2 a = *(const uint2*)(pinI + off);
            uint2 b = *(const uint2*)(pinI + off + 2);
            c[i][0] = a.x; c[i][1] = a.y; c[i][2] = b.x; c[i][3] = b.y;
            ihp[i][0] = *(const uint32_t*)(hI + off);
            ihp[i][1] = *(const uint32_t*)(hI + off + 2);
        }
    } else {
        #pragma unroll
        for (int i = 0; i < 4; ++i) {
            int gy = ry0 + i;
            unsigned short us[4];
            #pragma unroll
            for (int j = 0; j < 4; ++j) {
                int gxj = cx0 + j;
                bool in = ((unsigned)gy < (unsigned)HH) && ((unsigned)gxj < (unsigned)WW);
                c[i][j] = in ? pinI[(size_t)gy * WW + gxj] : 0u;
                us[j] = in ? *(const unsigned short*)(hI + (size_t)gy * WW + gxj)
                           : (unsigned short)0;
            }
            ihp[i][0] = (uint32_t)us[0] | ((uint32_t)us[1] << 16);
            ihp[i][1] = (uint32_t)us[2] | ((uint32_t)us[3] << 16);
        }
    }

    // ================= OUT_A (valid window r,c in [1,31]) =================
    float o[4][4];
    float accda = 0.f;
    {
        uint32_t ua[4];
        #pragma unroll
        for (int j = 0; j < 4; ++j) ua[j] = __shfl_up(c[3][j], 8, 64);  // lane-8's bottom row
        #pragma unroll
        for (int i = 0; i < 4; ++i) {
            uint32_t lw = __shfl_up(c[i][3], 1, 64);                    // lane-1's right col
            int gy = ry0 + i;
            bool r_ok = ((unsigned)(4 * ly + i - 2) < 28u) && (gy < HH);
            #pragma unroll
            for (int j = 0; j < 4; ++j) {
                float2 cf = h2f(c[i][j]);
                float up = (i > 0) ? h2f(c[i - 1][j]).x : h2f(ua[j]).x;
                float le = (j > 0) ? h2f(c[i][j - 1]).y : h2f(lw).y;
                float dv = -(cf.x + cf.y) + up + le;
                float2 i2 = h2f(ihp[i][j >> 1]);
                float imv = (j & 1) ? i2.y : i2.x;
                o[i][j] = imv + dv;
                bool own = r_ok && ((unsigned)(4 * lx + j - 2) < 28u) && (cx0 + j < WW);
                accda += own ? dv * dv : 0.f;
            }
        }
    }

    // ================= PT_A (valid r,c in [1,30]; zeroed outside image) =================
    uint32_t pa[4][4];
    float accna = 0.f;
    {
        float bel[4];
        #pragma unroll
        for (int j = 0; j < 4; ++j) bel[j] = __shfl_down(o[0][j], 8, 64);  // lane+8's top row
        #pragma unroll
        for (int i = 0; i < 4; ++i) {
            float rsh = __shfl_down(o[i][0], 1, 64);                       // lane+1's left col
            int gy = ry0 + i;
            bool r_ok = ((unsigned)(4 * ly + i - 2) < 28u) && (gy < HH);
            #pragma unroll
            for (int j = 0; j < 4; ++j) {
                int gxj = cx0 + j;
                float ov = o[i][j];
                float below = (i < 3) ? o[i + 1][j] : bel[j];
                float right = (j < 3) ? o[i][j + 1] : rsh;
                float g0 = (gy < HH - 1) ? below - ov : 0.f;
                float g1 = (gxj < WW - 1) ? right - ov : 0.f;
                float ss2 = g0 * g0 + g1 * g1;
                float nrm = (ss2 > 0.f) ? sqrtf(ss2) : 0.f;
                float inv = __builtin_amdgcn_rcpf(1.f + tw * nrm);
                float2 cf = h2f(c[i][j]);
                uint32_t pvv = f2h2((cf.x - TAU * g0) * inv, (cf.y - TAU * g1) * inv);
                bool vp = ((unsigned)gy < (unsigned)HH) && ((unsigned)gxj < (unsigned)WW);
                pa[i][j] = vp ? pvv : 0u;
                bool own = r_ok && ((unsigned)(4 * lx + j - 2) < 28u) && (gxj < WW);
                accna += own ? nrm : 0.f;
            }
        }
    }

    // ================= OUT_B (valid r,c in [2,30]) =================
    float ob[4][4];
    float accdb = 0.f;
    {
        uint32_t ua[4];
        #pragma unroll
        for (int j = 0; j < 4; ++j) ua[j] = __shfl_up(pa[3][j], 8, 64);
        #pragma unroll
        for (int i = 0; i < 4; ++i) {
            uint32_t lw = __shfl_up(pa[i][3], 1, 64);
            int gy = ry0 + i;
            bool r_ok = ((unsigned)(4 * ly + i - 2) < 28u) && (gy < HH);
            #pragma unroll
            for (int j = 0; j < 4; ++j) {
                float2 cf = h2f(pa[i][j]);
                float up = (i > 0) ? h2f(pa[i - 1][j]).x : h2f(ua[j]).x;
                float le = (j > 0) ? h2f(pa[i][j - 1]).y : h2f(lw).y;
                float dv = -(cf.x + cf.y) + up + le;
                float2 i2 = h2f(ihp[i][j >> 1]);
                float imv = (j & 1) ? i2.y : i2.x;
                ob[i][j] = imv + dv;
                bool own = r_ok && ((unsigned)(4 * lx + j - 2) < 28u) && (cx0 + j < WW);
                accdb += own ? dv * dv : 0.f;
            }
        }
    }

    // ================= PT_B (owned r,c in [2,29]) + store =================
    float accnb = 0.f;
    {
        float bel[4];
        #pragma unroll
        for (int j = 0; j < 4; ++j) bel[j] = __shfl_down(ob[0][j], 8, 64);
        #pragma unroll
        for (int i = 0; i < 4; ++i) {
            float rsh = __shfl_down(ob[i][0], 1, 64);
            int gy = ry0 + i;
            bool r_ok = ((unsigned)(4 * ly + i - 2) < 28u) && (gy < HH);
            uint32_t pv[4];
            #pragma unroll
            for (int j = 0; j < 4; ++j) {
                int gxj = cx0 + j;
                float ov = ob[i][j];
                float below = (i < 3) ? ob[i + 1][j] : bel[j];
                float right = (j < 3) ? ob[i][j + 1] : rsh;
                float g0 = (gy < HH - 1) ? below - ov : 0.f;
                float g1 = (gxj < WW - 1) ? right - ov : 0.f;
                float ss2 = g0 * g0 + g1 * g1;
                float nrm = (ss2 > 0.f) ? sqrtf(ss2) : 0.f;
                float inv = __builtin_amdgcn_rcpf(1.f + tw * nrm);
                float2 cf = h2f(pa[i][j]);
                uint32_t pvv = f2h2((cf.x - TAU * g0) * inv, (cf.y - TAU * g1) * inv);
                bool vp = ((unsigned)gy < (unsigned)HH) && ((unsigned)gxj < (unsigned)WW);
                pv[j] = vp ? pvv : 0u;
                bool own = r_ok && ((unsigned)(4 * lx + j - 2) < 28u) && (gxj < WW);
                accnb += own ? nrm : 0.f;
            }
            if (r_ok) {
                size_t off = (size_t)gy * WW + cx0;
                if (lx > 0 && cx0 < WW)
                    *(uint2*)(poutI + off) = make_uint2(pv[0], pv[1]);
                if (lx < 7 && cx0 + 2 < WW)
                    *(uint2*)(poutI + off + 2) = make_uint2(pv[2], pv[3]);
            }
        }
    }

    const int sOut = m & 1;
    red4_store(accda, accna, accdb, accnb,
               &sums[SUMIX(sOut, 0, im) + bid], &sums[SUMIX(sOut, 1, im) + bid],
               &sums[SUMIX(sOut, 2, im) + bid], &sums[SUMIX(sOut, 3, im) + bid], tid);
}

// =========================== epilogue (R10 logic, 100-partial head) ===========================
__global__ __launch_bounds__(256, 3) void tv_out(
    const float* __restrict__ img, float* __restrict__ out,
    const uint32_t* __restrict__ ptA, const uint32_t* __restrict__ ptB,
    const __half* __restrict__ imgh, const float* __restrict__ weight,
    const float* __restrict__ sc, const float* __restrict__ sums)
{
    const int im = blockIdx.z;
    const int tid = threadIdx.x;
    const float w = weight[im / CCH];

    __shared__ int2 shk;
    __shared__ float hsum[2][4];
    {
        const float* sI = sc;   // slot 0 = S_6 (written by m=4)
        int done = ((const int*)sI)[64 + im];
        int lastk = ((const int*)sI)[96 + im];
        float da = 0.f, na = 0.f, db = 0.f, nb = 0.f;
        if (!done && tid < 100) {
            da = sums[SUMIX(0, 0, im) + tid];
            na = sums[SUMIX(0, 1, im) + tid];
            db = sums[SUMIX(0, 2, im) + tid];
            nb = sums[SUMIX(0, 3, im) + tid];
        }
        if (tid < 128) {
            for (int off = 32; off > 0; off >>= 1) {
                da += __shfl_down(da, off, 64);
                na += __shfl_down(na, off, 64);
                db += __shfl_down(db, off, 64);
                nb += __shfl_down(nb, off, 64);
            }
            if ((tid & 63) == 0) {
                hsum[tid >> 6][0] = da; hsum[tid >> 6][1] = na;
                hsum[tid >> 6][2] = db; hsum[tid >> 6][3] = nb;
            }
        }
        __syncthreads();
        if (tid == 0) {
            if (!done) {
                float tda = hsum[0][0] + hsum[1][0];
                float tna = hsum[0][1] + hsum[1][1];
                float tdb = hsum[0][2] + hsum[1][2];
                float tnb = hsum[0][3] + hsum[1][3];
                float Eprev = sI[im], Einit = sI[32 + im];
                float Et = (tda + w * tna) / NUMEL;                // iter 7
                if (fabsf(Eprev - Et) < TVEPS * Einit) { done = 1; lastk = 7; }
                else {
                    Eprev = Et;
                    Et = (tdb + w * tnb) / NUMEL;                  // iter 8
                    if (fabsf(Eprev - Et) < TVEPS * Einit) { done = 1; lastk = 8; }
                }
            }
            shk.x = done; shk.y = lastk;
        }
    }
    __syncthreads();
    const int k = shk.x ? shk.y : 9;

    const float* imgI = img + (size_t)im * HH * WW;
    float* outI = out + (size_t)im * HH * WW;
    const int x0 = blockIdx.x * 64, y0 = blockIdx.y * 64;
    const int tx = tid & 15, ry = tid >> 4;
    const int gx = x0 + 4 * tx;

    if (k & 1) {
        // k in {1,3,5,7,9}: pt_{k-1} materialized. pt_0:A pt_2:B pt_4:A pt_6:B pt_8:A
        const uint32_t* p = ((((k - 1) >> 1) & 1) ? ptB : ptA) + (size_t)im * HH * WW;
        #pragma unroll
        for (int i = 0; i < 4; ++i) {
            int gy = y0 + ry + 16 * i;
            size_t off = (size_t)gy * WW + gx;
            uint4 cv = *(const uint4*)(p + off);
            uint4 uv = make_uint4(0u, 0u, 0u, 0u);
            if (gy > 0) uv = *(const uint4*)(p + off - WW);
            uint32_t lf = (gx > 0) ? p[off - 1] : 0u;
            float4 iv = *(const float4*)(imgI + off);
            uint32_t cc[4] = {cv.x, cv.y, cv.z, cv.w};
            uint32_t uu[4] = {uv.x, uv.y, uv.z, uv.w};
            uint32_t lt[4] = {lf, cv.x, cv.y, cv.z};
            float ivv[4] = {iv.x, iv.y, iv.z, iv.w};
            float r[4];
            #pragma unroll
            for (int j = 0; j < 4; ++j) {
                float2 cf = h2f(cc[j]);
                r[j] = ivv[j] + (-(cf.x + cf.y) + h2f(uu[j]).x + h2f(lt[j]).y);
            }
            *(float4*)(outI + off) = make_float4(r[0], r[1], r[2], r[3]);
        }
    } else {
        // k in {2,4,6,8}: recompute pt_{k-1} from preserved pt_{k-2}.
        const uint32_t* p = ((((k - 2) >> 1) & 1) ? ptB : ptA) + (size_t)im * HH * WW;
        const __half* hI = imgh + (size_t)im * HH * WW;
        const float tw = TAU / w;
        __shared__ Smem S;
        stage_pt_im(S, p, hI, x0, y0, tid);
        __syncthreads();
        phase_outA_x(S, tid);
        __syncthreads();
        phase_ptA_x(S, x0, y0, tid, tw);
        __syncthreads();
        #pragma unroll
        for (int i = 0; i < 4; ++i) {
            int gy = y0 + ry + 16 * i;
            int r = 2 + ry + 16 * i;
            size_t off = (size_t)gy * WW + gx;
            float4 iv = *(const float4*)(imgI + off);
            float ivv[4] = {iv.x, iv.y, iv.z, iv.w};
            float rr[4];
            #pragma unroll
            for (int j = 0; j < 4; ++j) {
                int cix = 2 + 4 * tx + j;
                float2 cf = h2f(S.PT[r * LSF + cix]);
                float up = h2f(S.PT[(r - 1) * LSF + cix]).x;
                float lf = h2f(S.PT[r * LSF + cix - 1]).y;
                rr[j] = ivv[j] + (-(cf.x + cf.y) + up + lf);
            }
            *(float4*)(outI + off) = make_float4(rr[0], rr[1], rr[2], rr[3]);
        }
    }
}

extern "C" void kernel_launch(void* const* d_in, const int* in_sizes, int n_in,
                              void* d_out, int out_size, void* d_ws, size_t ws_size,
                              hipStream_t stream)
{
    const float* img = (const float*)d_in[0];
    const float* weight = (const float*)d_in[1];
    float* out = (float*)d_out;
    float* sc = (float*)d_ws;
    float* sums = (float*)((char*)d_ws + 4096);
    __half* imgh = (__half*)((char*)d_ws + 131072);
    uint32_t* ptA = (uint32_t*)((char*)d_ws + 12713984);
    uint32_t* ptB = (uint32_t*)((char*)d_ws + 37879808);

    dim3 block(256);

    // iteration 0 -> pt_0 in A; accn into sums slot0/arr1 (64 partials)
    float* pn0 = sums + 1 * NIMG * 128;   // SUMIX(0,1,0) base
    tv_step0<<<dim3(8, 8, NIMG), block, 0, stream>>>(img, weight, imgh, ptA, pn0);

    // fused pairs m=1..4 cover iterations 1..8; m odd A->B, m even B->A
    for (int m = 1; m <= 4; ++m) {
        uint32_t* pin  = (m & 1) ? ptA : ptB;
        uint32_t* pout = (m & 1) ? ptB : ptA;
        tv_fused<<<dim3(NTB, NTB, NIMG), block, 0, stream>>>(m, imgh, weight, pin, pout, sc, sums);
    }

    // iteration 9's pt is dead; epilogue replays iters 7,8 and emits out.
    tv_out<<<dim3(8, 8, NIMG), block, 0, stream>>>(img, out, ptA, ptB, imgh, weight, sc, sums);
}